// Round 1
// baseline (20.608 us; speedup 1.0000x reference)
//
#include <hip/hip_runtime.h>
#include <math.h>

constexpr int BB  = 256;   // batch rows
constexpr int SS  = 512;   // slate size
constexpr int SP2 = SS + 2;

__device__ __forceinline__ float block_reduce256(float v, volatile float* sm) {
    // 256 threads = 4 waves of 64
    #pragma unroll
    for (int off = 32; off > 0; off >>= 1)
        v += __shfl_down(v, off, 64);
    const int wid  = threadIdx.x >> 6;
    const int lane = threadIdx.x & 63;
    __syncthreads();                 // protect sm reuse across calls
    if (lane == 0) sm[wid] = v;
    __syncthreads();
    return sm[0] + sm[1] + sm[2] + sm[3];   // broadcast to all threads
}

__device__ __forceinline__ float sigmoidf(float x) {
    return 1.0f / (1.0f + expf(-x));   // saturates cleanly to 0/1 in fp32
}

__global__ __launch_bounds__(256)
void ndcg_row_kernel(const float* __restrict__ y_pred,
                     const float* __restrict__ y_true,
                     const int*   __restrict__ qid,
                     const int*   __restrict__ indices,
                     const int*   __restrict__ num_pos,
                     const int*   __restrict__ num_item,
                     const float* __restrict__ ideal_dcg,
                     const float* __restrict__ u_buf,
                     const float* __restrict__ v_buf,
                     const float* __restrict__ lambda_q,
                     const float* __restrict__ r_q,
                     const float* __restrict__ s_q,
                     float* __restrict__ ws_row,
                     float* __restrict__ ws_a) {
    __shared__ float sh_yp[SS];   // y_pred, zeroed at padded docs
    __shared__ float sh_ys[SS];   // y_pred with -1e4 sentinel at padded docs
    __shared__ float sh_G[SS];    // gain 2^max(yt,0)-1, 0 at padded
    __shared__ float sm[4];

    const int b = blockIdx.x;
    const int t = threadIdx.x;

    // ---- Phase A: stage the row ----
    float finv[2];
    #pragma unroll
    for (int k = 0; k < 2; ++k) {
        const int s   = t + k * 256;
        const float yt  = y_true[b * SS + s];
        const float ypv = y_pred[b * SS + s];
        const float fin = (yt != -1.0f) ? 1.0f : 0.0f;
        finv[k]   = fin;
        sh_yp[s]  = fin * ypv;
        sh_ys[s]  = (fin != 0.0f) ? ypv : -1.0e4f;
        sh_G[s]   = (fin != 0.0f) ? (exp2f(fmaxf(yt, 0.0f)) - 1.0f) : 0.0f;
    }
    __syncthreads();
    const float n_fin = block_reduce256(finv[0] + finv[1], sm);

    // ---- Phase B: pairwise squared hinge g[i] ----
    float g[2];
    #pragma unroll
    for (int k = 0; k < 2; ++k) {
        const int i = t + k * 256;
        const float yi1 = 1.0f - sh_yp[i];          // d = yp[j] - yp[i] + 1
        float a0 = 0.f, a1 = 0.f, a2 = 0.f, a3 = 0.f;
        for (int j = 0; j < SS; j += 4) {           // LDS broadcast reads
            const float h0 = fmaxf(sh_ys[j + 0] + yi1, 0.0f);
            const float h1 = fmaxf(sh_ys[j + 1] + yi1, 0.0f);
            const float h2 = fmaxf(sh_ys[j + 2] + yi1, 0.0f);
            const float h3 = fmaxf(sh_ys[j + 3] + yi1, 0.0f);
            a0 = fmaf(h0, h0, a0); a1 = fmaf(h1, h1, a1);
            a2 = fmaf(h2, h2, a2); a3 = fmaf(h3, h3, a3);
        }
        g[k] = finv[k] * (((a0 + a1) + (a2 + a3)) / n_fin) + 1e-10f;
    }

    // ---- Phase C: per-item terms + row reductions ----
    const int   qb  = qid[b * SS] + 1;
    const float lam = lambda_q[qb];
    const float ni  = (float)num_item[b];
    const float sqv = s_q[qb];

    float Shess = 0.f, Sphi = 0.f, Shy = 0.f, P1 = 0.f, P2 = 0.f, P3 = 0.f;
    #pragma unroll
    for (int k = 0; k < 2; ++k) {
        const int s   = t + k * 256;
        const int qf  = qid[b * SS + s] + 1;
        const int idf = indices[b * SS + s] + 1;
        const int ui  = qf * SP2 + idf;
        const float u_old = u_buf[ui];
        const float v_old = v_buf[ui];
        const float nug   = u_old - g[k];                    // u_old - stopgrad(g)
        const float v_new = 0.9f * v_old + 0.1f * nug;       // (1-GAMMA_V), GAMMA_V
        const float g_u   = u_old - 0.01f * v_new;           // u_new (ETA1)
        const float t2    = fmaf(ni, g_u, 2.0f);             // 2 + ni*g_u  (>0 always)
        const float l2t   = log2f(t2);
        const float Gs    = sh_G[s];
        const float fin   = finv[k];

        float nfg = Gs * ni / (l2t * l2t * t2 * 0.6931471805599453f);

        const float pld  = (fin != 0.0f) ? (y_pred[b * SS + s] - lam) : 0.0f;
        const float sig1 = sigmoidf(pld * 1000.0f);          // pld / TAU1
        const float siga = sigmoidf(pld * 2.0f);             // pld * SIG_ALPHA
        nfg *= 2.0f * siga;                                   // C_SIG * sig_a
        const float w1 = 2.0f * siga * (1.0f - siga);
        const float tt = sig1 * (1.0f - sig1) * 1000.0f;      // /TAU1
        const float fgu = -Gs / l2t;
        const float ypz = sh_yp[s];

        Shess += fin * tt;
        Sphi  += fin * (Gs / l2t);
        Shy   += fin * tt * ypz;
        P1  = fmaf(nfg, g[k], P1);
        P2 += w1 * fgu * ypz;
        P3 += w1 * fgu;
    }
    Shess = block_reduce256(Shess, sm);
    Sphi  = block_reduce256(Sphi,  sm);
    Shy   = block_reduce256(Shy,   sm);
    P1    = block_reduce256(P1,    sm);
    P2    = block_reduce256(P2,    sm);
    P3    = block_reduce256(P3,    sm);

    if (t == 0) {
        const float L_hess = 1e-4f + Shess / n_fin;                 // TAU2 + ...
        const float nsp    = L_hess * sqv + Sphi / n_fin;
        const float r_new  = 0.9f * r_q[qb] + 0.1f * nsp;           // GAMMA_R
        const float s_new  = sqv - 0.01f * r_new;                   // ETA1
        const float hess   = (Shy / n_fin) / s_new;
        const float row_sum = P1 + P2 - hess * P3;
        ws_row[b] = row_sum / (float)SS;                            // mean over S
        ws_a[b]   = (float)num_pos[b] / (ideal_dcg[b] + 1e-10f);
    }
}

__global__ __launch_bounds__(256)
void ndcg_final_kernel(const float* __restrict__ ws_row,
                       const float* __restrict__ ws_a,
                       float* __restrict__ out) {
    __shared__ float sm[4];
    const int t = threadIdx.x;
    const float r = block_reduce256(ws_row[t], sm);
    const float a = block_reduce256(ws_a[t],  sm);
    if (t == 0) out[0] = (a / (float)BB) * (r / (float)BB);
}

extern "C" void kernel_launch(void* const* d_in, const int* in_sizes, int n_in,
                              void* d_out, int out_size, void* d_ws, size_t ws_size,
                              hipStream_t stream) {
    const float* y_pred    = (const float*)d_in[0];
    const float* y_true    = (const float*)d_in[1];
    const int*   qid       = (const int*)  d_in[2];
    const int*   indices   = (const int*)  d_in[3];
    const int*   num_pos   = (const int*)  d_in[4];
    const int*   num_item  = (const int*)  d_in[5];
    const float* ideal_dcg = (const float*)d_in[6];
    const float* u_buf     = (const float*)d_in[7];
    const float* v_buf     = (const float*)d_in[8];
    const float* lambda_q  = (const float*)d_in[9];
    // d_in[10] = z_q (unused by the forward path)
    const float* r_q       = (const float*)d_in[11];
    const float* s_q       = (const float*)d_in[12];

    float* wsf = (float*)d_ws;            // [0,BB) row means, [BB,2BB) num_pos/idcg

    ndcg_row_kernel<<<BB, 256, 0, stream>>>(y_pred, y_true, qid, indices,
                                            num_pos, num_item, ideal_dcg,
                                            u_buf, v_buf, lambda_q, r_q, s_q,
                                            wsf, wsf + BB);
    ndcg_final_kernel<<<1, 256, 0, stream>>>(wsf, wsf + BB, (float*)d_out);
}